// Round 6
// baseline (196.268 us; speedup 1.0000x reference)
//
#include <hip/hip_runtime.h>

// CrossScaleAttention: out = softmax(l2n(Q) l2n(K)^T * 32^-0.5) V
// B=4, Nq=Nk=4096, D=256, fp32 in/out.
// |scores| <= 0.1768 => no online max: O += exp(S) V, l += rowsum, divide at end.
// R6: R3's exact single-buffer barrier schedule (it measured best), concurrency
//     raised to 3 blocks/CU via KSPLIT=4 (grid 1024) + 40.5 KB LDS; Opart bf16.

#define NQ 4096
#define DIM 256
#define NROWS 16384      // B*NQ
#define BM 64            // q rows per workgroup
#define BN 64            // keys per iteration
#define KSPLIT 4
#define NITER 16         // (4096/KSPLIT)/BN
#define PSTRIDE 68       // Plds row stride (ushorts): 64 + 4 pad (measured 0 conflicts)

typedef __attribute__((ext_vector_type(8))) short bf16x8;
typedef __attribute__((ext_vector_type(4))) float f32x4;
typedef __attribute__((ext_vector_type(16))) float f32x16;

__device__ __forceinline__ unsigned short f2bf(float f) {
  unsigned int u = __float_as_uint(f);
  u += 0x7fffu + ((u >> 16) & 1u);            // RNE
  return (unsigned short)(u >> 16);
}

__device__ __forceinline__ float bf2f(unsigned short h) {
  return __uint_as_float((unsigned int)h << 16);
}

// pack two positive floats to bf16 pair (round half up; ties-only deviation from RNE)
__device__ __forceinline__ unsigned int pack2bf(float a, float b) {
  unsigned int ua = __float_as_uint(a) + 0x8000u;
  unsigned int ub = __float_as_uint(b) + 0x8000u;
  return __builtin_amdgcn_perm(ub, ua, 0x07060302u);  // [ua.hi16 | ub.hi16]
}

__device__ __forceinline__ void gload16(const void* g, void* l) {
  __builtin_amdgcn_global_load_lds(
      (const __attribute__((address_space(1))) unsigned int*)g,
      (__attribute__((address_space(3))) unsigned int*)l, 16, 0, 0);
}

// ---------------------------------------------------------------------------
// prep: blocks [0,4096): Q rows -> row-major bf16, scale folded (SCALE*log2e).
//       [4096,4352): K 64-row tiles -> LDS transpose -> chunk-major Kfm
//         [tile][c:32][n:64][8], 32 KB contiguous per tile, coalesced.
//       [4352,5376): V 16-row tiles -> B-frag-major Vfm via LDS transpose.
// ---------------------------------------------------------------------------
__global__ __launch_bounds__(256) void prep(
    const float* __restrict__ Q, const float* __restrict__ K,
    const float* __restrict__ V,
    unsigned short* __restrict__ Qrm, unsigned short* __restrict__ Kfm,
    unsigned short* __restrict__ Vfm)
{
  __shared__ unsigned short vt[64 * 264];
  const int blk = blockIdx.x, tid = threadIdx.x;
  const int wave = tid >> 6, lane = tid & 63;
  if (blk < 4096) {
    const int R = blk * 4 + wave;
    float4 v = *(const float4*)(Q + (size_t)R * DIM + lane * 4);
    float ss = v.x*v.x + v.y*v.y + v.z*v.z + v.w*v.w;
    #pragma unroll
    for (int off = 1; off < 64; off <<= 1) ss += __shfl_xor(ss, off, 64);
    float scale = (0.17677669529663687f * 1.4426950408889634f)   // SCALE*log2e
                  / fmaxf(sqrtf(ss), 1e-12f);
    ushort4 o;
    o.x = f2bf(v.x*scale); o.y = f2bf(v.y*scale);
    o.z = f2bf(v.z*scale); o.w = f2bf(v.w*scale);
    *(ushort4*)(Qrm + (size_t)R * DIM + lane * 4) = o;
  } else if (blk < 4352) {
    const int kt = blk - 4096;
    #pragma unroll
    for (int i = 0; i < 16; i++) {
      const int n = i*4 + wave;
      float4 v = *(const float4*)(K + ((size_t)kt*64 + n) * DIM + lane * 4);
      float ss = v.x*v.x + v.y*v.y + v.z*v.z + v.w*v.w;
      #pragma unroll
      for (int off = 1; off < 64; off <<= 1) ss += __shfl_xor(ss, off, 64);
      float scale = 1.0f / fmaxf(sqrtf(ss), 1e-12f);
      ushort4 o;
      o.x = f2bf(v.x*scale); o.y = f2bf(v.y*scale);
      o.z = f2bf(v.z*scale); o.w = f2bf(v.w*scale);
      *(ushort4*)(vt + n*264 + lane*4) = o;
    }
    __syncthreads();
    #pragma unroll
    for (int s = 0; s < 8; s++) {
      const int ch = tid + 256*s;          // 2048 chunks of 8 ushorts
      const int c = ch >> 6, n = ch & 63;
      bf16x8 val = *(const bf16x8*)(vt + n*264 + c*8);
      *(bf16x8*)(Kfm + (size_t)kt*16384 + (size_t)ch*8) = val;   // coalesced
    }
  } else {
    const int NS = blk - 4352;
    #pragma unroll
    for (int i = 0; i < 4; i++) {
      const int e = tid + 256*i;
      const int nl = e >> 6, d = (e & 63) * 4;
      float4 v = *(const float4*)(V + ((size_t)NS*16 + nl)*DIM + d);
      ushort4 o;
      o.x = f2bf(v.x); o.y = f2bf(v.y); o.z = f2bf(v.z); o.w = f2bf(v.w);
      *(ushort4*)(vt + nl*264 + d) = o;
    }
    __syncthreads();
    #pragma unroll
    for (int i = 0; i < 2; i++) {
      const int ch = tid + 256*i;
      const int db = ch >> 6, ln = ch & 63;
      const int row0 = (ln >> 5) * 8, dd = db*32 + (ln & 31);
      ushort4 a, b;
      a.x = vt[(row0+0)*264 + dd]; a.y = vt[(row0+1)*264 + dd];
      a.z = vt[(row0+2)*264 + dd]; a.w = vt[(row0+3)*264 + dd];
      b.x = vt[(row0+4)*264 + dd]; b.y = vt[(row0+5)*264 + dd];
      b.z = vt[(row0+6)*264 + dd]; b.w = vt[(row0+7)*264 + dd];
      size_t base = ((size_t)(NS*8 + db)*64 + ln)*8;
      *(ushort4*)(Vfm + base)     = a;
      *(ushort4*)(Vfm + base + 4) = b;
    }
  }
}

// ---------------------------------------------------------------------------
// attn: grid=1024, 256 thr (4 waves), 3 blocks/CU (LDS 40.5 KB, VGPR<=128).
// blk&15 -> (b,ks): same-XCD blocks share K/V quarters (L2 locality).
// Schedule per iter (R3's, measured best): sync / S / P / sync / stage(kt+1) / O.
// S^T-phase: mfma16x16x32(A=kf, B=qf); wave (mi=w&1, ni=w>>1) = 32n x 32m.
// O-phase: mfma32x32x16; wave w owns 64d, full 64m. Opart stored as bf16.
// ---------------------------------------------------------------------------
__global__ __launch_bounds__(256, 4) void attn(
    const unsigned short* __restrict__ Qrm,
    const unsigned short* __restrict__ Kfm,
    const unsigned short* __restrict__ Vfm,
    unsigned short* __restrict__ Opart, float* __restrict__ lpart)
{
  __shared__ unsigned short Klds[32 * 64 * 8];     // 32 KB chunk-major
  __shared__ unsigned short Plds[BM * PSTRIDE];    // 8704 B row-major padded

  const int tid = threadIdx.x, wave = tid >> 6, lane = tid & 63;
  const int l15 = lane & 15, l4 = lane >> 4;
  const int blk = blockIdx.x;
  const int g = blk & 15, qt = blk >> 4;
  const int b = g >> 2, ks = g & 3;
  const int Rq0 = b*NQ + qt*BM;
  const int n0base = b*NQ + ks*(NQ/KSPLIT);
  const int mi = wave & 1, ni = wave >> 1;

  // Q B-frags: q-row = Rq0 + mi*32 + mt*16 + l15, k = kg*32 + l4*8 + j
  bf16x8 qf[2][8];
  #pragma unroll
  for (int mt = 0; mt < 2; mt++) {
    const unsigned short* qrow = Qrm + (size_t)(Rq0 + mi*32 + mt*16 + l15) * DIM + l4*8;
    #pragma unroll
    for (int kg = 0; kg < 8; kg++)
      qf[mt][kg] = *(const bf16x8*)(qrow + kg*32);
  }

  f32x16 oacc[2][2] = {};   // [mt2][dt]
  float lacc[2] = {};       // [mt]

  auto stage = [&](int kt) {
    const unsigned short* src = Kfm + (size_t)((n0base + kt*BN) >> 6) * (32*64*8);
    #pragma unroll
    for (int jj = 0; jj < 4; jj++) {
      const int c = wave*8 + jj*2;      // 8 chunks (1 KB each) per wave
      gload16(src + (size_t)c*512 + lane*8,     Klds + (size_t)c*512);
      gload16(src + (size_t)(c+1)*512 + lane*8, Klds + (size_t)(c+1)*512);
    }
  };

  stage(0);

  for (int kt = 0; kt < NITER; kt++) {
    __syncthreads();   // K tile ready (drains staging); prev P fully consumed

    // ---- S^T = Khat Qhat^T (scale folded into Q) ----
    f32x4 sacc[2][2] = {};   // [nt][mt]
    #pragma unroll
    for (int kg = 0; kg < 8; kg++) {
      bf16x8 kf[2];
      #pragma unroll
      for (int nt = 0; nt < 2; nt++) {
        const int nrow = ni*32 + nt*16 + l15;
        const int c = kg*4 + l4;
        kf[nt] = *(const bf16x8*)(Klds + ((size_t)(c*64 + nrow))*8);
      }
      #pragma unroll
      for (int nt = 0; nt < 2; nt++)
        #pragma unroll
        for (int mt = 0; mt < 2; mt++)
          sacc[nt][mt] = __builtin_amdgcn_mfma_f32_16x16x32_bf16(
              kf[nt], qf[mt][kg], sacc[nt][mt], 0, 0, 0);
    }

    // ---- P = exp2(S); row-sums; packed b64 writes to Plds[m][n] ----
    #pragma unroll
    for (int nt = 0; nt < 2; nt++)
      #pragma unroll
      for (int mt = 0; mt < 2; mt++) {
        float p0 = __builtin_amdgcn_exp2f(sacc[nt][mt][0]);
        float p1 = __builtin_amdgcn_exp2f(sacc[nt][mt][1]);
        float p2 = __builtin_amdgcn_exp2f(sacc[nt][mt][2]);
        float p3 = __builtin_amdgcn_exp2f(sacc[nt][mt][3]);
        lacc[mt] += (p0 + p1) + (p2 + p3);
        uint2 pk;
        pk.x = pack2bf(p0, p1);
        pk.y = pack2bf(p2, p3);
        const int m = mi*32 + mt*16 + l15;
        const int n = ni*32 + nt*16 + 4*l4;
        *(uint2*)(Plds + m*PSTRIDE + n) = pk;
      }

    __syncthreads();   // P visible; K reads done -> K buffer free

    if (kt + 1 < NITER) stage(kt + 1);   // lands during O-phase + next top barrier

    // ---- O += P V ----
    const int NB0 = (n0base + kt*BN) >> 4;
    #pragma unroll
    for (int kstep = 0; kstep < 4; kstep++) {
      bf16x8 pf[2], vf[2];
      #pragma unroll
      for (int mt2 = 0; mt2 < 2; mt2++)
        pf[mt2] = *(const bf16x8*)(Plds + (mt2*32 + (lane & 31))*PSTRIDE
                                   + kstep*16 + 8*(lane >> 5));
      #pragma unroll
      for (int dt = 0; dt < 2; dt++) {
        const int db = wave*2 + dt;
        vf[dt] = *(const bf16x8*)(Vfm + ((size_t)((NB0 + kstep)*8 + db)*64 + lane)*8);
      }
      #pragma unroll
      for (int mt2 = 0; mt2 < 2; mt2++)
        #pragma unroll
        for (int dt = 0; dt < 2; dt++)
          oacc[mt2][dt] = __builtin_amdgcn_mfma_f32_32x32x16_bf16(
              pf[mt2], vf[dt], oacc[mt2][dt], 0, 0, 0);
    }
  }

  // ---- epilogue: l row-sums (reduce over l4 groups) ----
  #pragma unroll
  for (int mt = 0; mt < 2; mt++) {
    float s = lacc[mt];
    s += __shfl_xor(s, 16, 64);
    s += __shfl_xor(s, 32, 64);
    if (l4 == 0)
      lpart[(size_t)(ks*2 + ni)*NROWS + Rq0 + mi*32 + mt*16 + l15] = s;
  }

  // ---- epilogue: O stores (bf16, 64B per 32-lane group per store) ----
  #pragma unroll
  for (int mt2 = 0; mt2 < 2; mt2++)
    #pragma unroll
    for (int dt = 0; dt < 2; dt++)
      #pragma unroll
      for (int reg = 0; reg < 16; reg++) {
        const int m = mt2*32 + 4*(lane >> 5) + (reg & 3) + 8*(reg >> 2);
        const int d = wave*64 + dt*32 + (lane & 31);
        Opart[((size_t)(ks*NROWS + Rq0 + m))*DIM + d] = f2bf(oacc[mt2][dt][reg]);
      }
}

// ---------------------------------------------------------------------------
// combine: out = (sum_{s<4} O_s) / (sum_{s<8} l_s)
// ---------------------------------------------------------------------------
__global__ __launch_bounds__(256) void combine(
    const unsigned short* __restrict__ Opart, const float* __restrict__ lpart,
    float* __restrict__ out)
{
  const size_t idx = (size_t)blockIdx.x*256 + threadIdx.x;
  const size_t e = idx*4;
  const int R = (int)(e >> 8);
  float acc[4] = {0.f, 0.f, 0.f, 0.f};
  #pragma unroll
  for (int s = 0; s < 4; s++) {
    ushort4 o = *(const ushort4*)(Opart + (size_t)s*NROWS*DIM + e);
    acc[0] += bf2f(o.x); acc[1] += bf2f(o.y);
    acc[2] += bf2f(o.z); acc[3] += bf2f(o.w);
  }
  float ls = 0.f;
  #pragma unroll
  for (int s = 0; s < 8; s++) ls += lpart[(size_t)s*NROWS + R];
  float inv = 1.0f / ls;
  float4 o;
  o.x = acc[0]*inv; o.y = acc[1]*inv; o.z = acc[2]*inv; o.w = acc[3]*inv;
  *(float4*)(out + e) = o;
}

extern "C" void kernel_launch(void* const* d_in, const int* in_sizes, int n_in,
                              void* d_out, int out_size, void* d_ws, size_t ws_size,
                              hipStream_t stream) {
  const float* Q = (const float*)d_in[0];
  const float* K = (const float*)d_in[1];
  const float* V = (const float*)d_in[2];
  char* ws = (char*)d_ws;
  // ws layout: Qrm 8 MiB | Kfm 8 MiB | Vfm 8 MiB | Opart(bf16) 32 MiB | lpart 512 KiB
  unsigned short* Qrm  = (unsigned short*)(ws);
  unsigned short* Kfm  = (unsigned short*)(ws + 8388608);
  unsigned short* Vfm  = (unsigned short*)(ws + 16777216);
  unsigned short* Opart = (unsigned short*)(ws + 25165824);
  float* lpart = (float*)(ws + 58720256);

  prep<<<5376, 256, 0, stream>>>(Q, K, V, Qrm, Kfm, Vfm);
  attn<<<1024, 256, 0, stream>>>(Qrm, Kfm, Vfm, Opart, lpart);
  combine<<<4096, 256, 0, stream>>>(Opart, lpart, (float*)d_out);
}

// Round 7
// 173.503 us; speedup vs baseline: 1.1312x; 1.1312x over previous
//
#include <hip/hip_runtime.h>

// CrossScaleAttention: out = softmax(l2n(Q) l2n(K)^T * 32^-0.5) V
// B=4, Nq=Nk=4096, D=256, fp32 in/out.
// |scores| <= 0.1768 => no online max: O += exp(S) V, l += rowsum, divide at end.
// R7: attn K-loop identical to R3 (best measured: 85us). Q-normalize fused into
//     attn prologue (via Klds); Opart stored bf16 (R6-proven); prep = K/V only.

#define NQ 4096
#define DIM 256
#define NROWS 16384      // B*NQ
#define BM 64            // q rows per workgroup
#define BN 64            // keys per iteration
#define KSPLIT 2
#define NITER 32         // (4096/KSPLIT)/BN
#define PSTRIDE 68       // Plds row stride (ushorts): 64 + 4 pad (measured 0 conflicts)

typedef __attribute__((ext_vector_type(8))) short bf16x8;
typedef __attribute__((ext_vector_type(4))) float f32x4;
typedef __attribute__((ext_vector_type(16))) float f32x16;

__device__ __forceinline__ unsigned short f2bf(float f) {
  unsigned int u = __float_as_uint(f);
  u += 0x7fffu + ((u >> 16) & 1u);            // RNE
  return (unsigned short)(u >> 16);
}

__device__ __forceinline__ float bf2f(unsigned short h) {
  return __uint_as_float((unsigned int)h << 16);
}

// pack two positive floats to bf16 pair (round half up; ties-only deviation from RNE)
__device__ __forceinline__ unsigned int pack2bf(float a, float b) {
  unsigned int ua = __float_as_uint(a) + 0x8000u;
  unsigned int ub = __float_as_uint(b) + 0x8000u;
  return __builtin_amdgcn_perm(ub, ua, 0x07060302u);  // [ua.hi16 | ub.hi16]
}

__device__ __forceinline__ void gload16(const void* g, void* l) {
  __builtin_amdgcn_global_load_lds(
      (const __attribute__((address_space(1))) unsigned int*)g,
      (__attribute__((address_space(3))) unsigned int*)l, 16, 0, 0);
}

// ---------------------------------------------------------------------------
// prep (K/V only, balanced blocks):
//  [0,512):    K 32-row half-tiles -> normalize -> LDS -> chunk-major Kfm
//              [tile64][c:32][n:64][8], coalesced 512B store runs.
//  [512,1536): V 16-row tiles -> B-frag-major Vfm via LDS transpose.
// ---------------------------------------------------------------------------
__global__ __launch_bounds__(256) void prep(
    const float* __restrict__ K, const float* __restrict__ V,
    unsigned short* __restrict__ Kfm, unsigned short* __restrict__ Vfm)
{
  __shared__ unsigned short vt[32 * 264];
  const int blk = blockIdx.x, tid = threadIdx.x;
  const int wave = tid >> 6, lane = tid & 63;
  if (blk < 512) {
    const int kt2 = blk;              // 32-row unit
    const int kt = kt2 >> 1, h = kt2 & 1;
    #pragma unroll
    for (int i = 0; i < 8; i++) {
      const int r = wave*8 + i;       // 0..31 local row
      float4 v = *(const float4*)(K + ((size_t)kt2*32 + r) * DIM + lane * 4);
      float ss = v.x*v.x + v.y*v.y + v.z*v.z + v.w*v.w;
      #pragma unroll
      for (int off = 1; off < 64; off <<= 1) ss += __shfl_xor(ss, off, 64);
      float scale = 1.0f / fmaxf(sqrtf(ss), 1e-12f);
      ushort4 o;
      o.x = f2bf(v.x*scale); o.y = f2bf(v.y*scale);
      o.z = f2bf(v.z*scale); o.w = f2bf(v.w*scale);
      *(ushort4*)(vt + r*264 + lane*4) = o;
    }
    __syncthreads();
    #pragma unroll
    for (int s = 0; s < 4; s++) {
      const int ch = tid + 256*s;          // 1024 chunks of 8 ushorts
      const int c = ch >> 5, r = ch & 31;
      const int n = h*32 + r;
      bf16x8 val = *(const bf16x8*)(vt + r*264 + c*8);
      *(bf16x8*)(Kfm + (size_t)kt*16384 + (size_t)(c*64 + n)*8) = val;
    }
  } else {
    const int NS = blk - 512;
    #pragma unroll
    for (int i = 0; i < 4; i++) {
      const int e = tid + 256*i;
      const int nl = e >> 6, d = (e & 63) * 4;
      float4 v = *(const float4*)(V + ((size_t)NS*16 + nl)*DIM + d);
      ushort4 o;
      o.x = f2bf(v.x); o.y = f2bf(v.y); o.z = f2bf(v.z); o.w = f2bf(v.w);
      *(ushort4*)(vt + nl*264 + d) = o;
    }
    __syncthreads();
    #pragma unroll
    for (int i = 0; i < 2; i++) {
      const int ch = tid + 256*i;
      const int db = ch >> 6, ln = ch & 63;
      const int row0 = (ln >> 5) * 8, dd = db*32 + (ln & 31);
      ushort4 a, b;
      a.x = vt[(row0+0)*264 + dd]; a.y = vt[(row0+1)*264 + dd];
      a.z = vt[(row0+2)*264 + dd]; a.w = vt[(row0+3)*264 + dd];
      b.x = vt[(row0+4)*264 + dd]; b.y = vt[(row0+5)*264 + dd];
      b.z = vt[(row0+6)*264 + dd]; b.w = vt[(row0+7)*264 + dd];
      size_t base = ((size_t)(NS*8 + db)*64 + ln)*8;
      *(ushort4*)(Vfm + base)     = a;
      *(ushort4*)(Vfm + base + 4) = b;
    }
  }
}

// ---------------------------------------------------------------------------
// attn: grid=512, 256 thr (4 waves), 2 blocks/CU. blk&7 -> (b,ks) for L2 locality.
// Prologue: normalize this block's 64 Q rows (fp32 in), round-trip via Klds to
// distribute MFMA B-frags; then K-loop IDENTICAL to R3 (best measured):
//   sync / S / P / sync / stage(kt+1) / O.
// Epilogue: Opart stored bf16 (R6-proven numerics).
// ---------------------------------------------------------------------------
__global__ __launch_bounds__(256, 2) void attn(
    const float* __restrict__ Qg,
    const unsigned short* __restrict__ Kfm,
    const unsigned short* __restrict__ Vfm,
    unsigned short* __restrict__ Opart, float* __restrict__ lpart)
{
  __shared__ unsigned short Klds[32 * 64 * 8];     // 32 KB chunk-major (also Q staging)
  __shared__ unsigned short Plds[BM * PSTRIDE];    // 8704 B row-major padded

  const int tid = threadIdx.x, wave = tid >> 6, lane = tid & 63;
  const int l15 = lane & 15, l4 = lane >> 4;
  const int blk = blockIdx.x;
  const int g = blk & 7, qt = blk >> 3;
  const int b = g >> 1, ks = g & 1;
  const int Rq0 = b*NQ + qt*BM;
  const int n0base = b*NQ + ks*(NQ/KSPLIT);
  const int mi = wave & 1, ni = wave >> 1;

  // ---- prologue: normalize 64 Q rows into Klds (used as Q staging) ----
  {
    unsigned short* Qlds = Klds;
    #pragma unroll
    for (int i = 0; i < 16; i++) {
      const int r = wave*16 + i;
      float4 v = *(const float4*)(Qg + (size_t)(Rq0 + r)*DIM + lane*4);
      float ss = v.x*v.x + v.y*v.y + v.z*v.z + v.w*v.w;
      #pragma unroll
      for (int off = 1; off < 64; off <<= 1) ss += __shfl_xor(ss, off, 64);
      float scale = (0.17677669529663687f * 1.4426950408889634f)   // SCALE*log2e
                    / fmaxf(sqrtf(ss), 1e-12f);
      ushort4 o;
      o.x = f2bf(v.x*scale); o.y = f2bf(v.y*scale);
      o.z = f2bf(v.z*scale); o.w = f2bf(v.w*scale);
      *(ushort4*)(Qlds + r*DIM + lane*4) = o;
    }
  }
  __syncthreads();

  // Q B-frags from Qlds: local row = mi*32 + mt*16 + l15, k = kg*32 + l4*8
  bf16x8 qf[2][8];
  #pragma unroll
  for (int mt = 0; mt < 2; mt++) {
    const unsigned short* qrow = Klds + (mi*32 + mt*16 + l15)*DIM + l4*8;
    #pragma unroll
    for (int kg = 0; kg < 8; kg++)
      qf[mt][kg] = *(const bf16x8*)(qrow + kg*32);
  }
  __syncthreads();   // all Q reads done before stage(0) overwrites Klds

  f32x16 oacc[2][2] = {};   // [mt2][dt]
  float lacc[2] = {};       // [mt]

  auto stage = [&](int kt) {
    const unsigned short* src = Kfm + (size_t)((n0base + kt*BN) >> 6) * (32*64*8);
    #pragma unroll
    for (int jj = 0; jj < 4; jj++) {
      const int c = wave*8 + jj*2;      // 8 chunks (1 KB each) per wave
      gload16(src + (size_t)c*512 + lane*8,     Klds + (size_t)c*512);
      gload16(src + (size_t)(c+1)*512 + lane*8, Klds + (size_t)(c+1)*512);
    }
  };

  stage(0);

  for (int kt = 0; kt < NITER; kt++) {
    __syncthreads();   // K tile ready (drains staging); prev P fully consumed

    // ---- S^T = Khat Qhat^T (scale folded into Q) ----
    f32x4 sacc[2][2] = {};   // [nt][mt]
    #pragma unroll
    for (int kg = 0; kg < 8; kg++) {
      bf16x8 kf[2];
      #pragma unroll
      for (int nt = 0; nt < 2; nt++) {
        const int nrow = ni*32 + nt*16 + l15;
        const int c = kg*4 + l4;
        kf[nt] = *(const bf16x8*)(Klds + ((size_t)(c*64 + nrow))*8);
      }
      #pragma unroll
      for (int nt = 0; nt < 2; nt++)
        #pragma unroll
        for (int mt = 0; mt < 2; mt++)
          sacc[nt][mt] = __builtin_amdgcn_mfma_f32_16x16x32_bf16(
              kf[nt], qf[mt][kg], sacc[nt][mt], 0, 0, 0);
    }

    // ---- P = exp2(S); row-sums; packed b64 writes to Plds[m][n] ----
    #pragma unroll
    for (int nt = 0; nt < 2; nt++)
      #pragma unroll
      for (int mt = 0; mt < 2; mt++) {
        float p0 = __builtin_amdgcn_exp2f(sacc[nt][mt][0]);
        float p1 = __builtin_amdgcn_exp2f(sacc[nt][mt][1]);
        float p2 = __builtin_amdgcn_exp2f(sacc[nt][mt][2]);
        float p3 = __builtin_amdgcn_exp2f(sacc[nt][mt][3]);
        lacc[mt] += (p0 + p1) + (p2 + p3);
        uint2 pk;
        pk.x = pack2bf(p0, p1);
        pk.y = pack2bf(p2, p3);
        const int m = mi*32 + mt*16 + l15;
        const int n = ni*32 + nt*16 + 4*l4;
        *(uint2*)(Plds + m*PSTRIDE + n) = pk;
      }

    __syncthreads();   // P visible; K reads done -> K buffer free

    if (kt + 1 < NITER) stage(kt + 1);   // lands during O-phase + next top barrier

    // ---- O += P V ----
    const int NB0 = (n0base + kt*BN) >> 4;
    #pragma unroll
    for (int kstep = 0; kstep < 4; kstep++) {
      bf16x8 pf[2], vf[2];
      #pragma unroll
      for (int mt2 = 0; mt2 < 2; mt2++)
        pf[mt2] = *(const bf16x8*)(Plds + (mt2*32 + (lane & 31))*PSTRIDE
                                   + kstep*16 + 8*(lane >> 5));
      #pragma unroll
      for (int dt = 0; dt < 2; dt++) {
        const int db = wave*2 + dt;
        vf[dt] = *(const bf16x8*)(Vfm + ((size_t)((NB0 + kstep)*8 + db)*64 + lane)*8);
      }
      #pragma unroll
      for (int mt2 = 0; mt2 < 2; mt2++)
        #pragma unroll
        for (int dt = 0; dt < 2; dt++)
          oacc[mt2][dt] = __builtin_amdgcn_mfma_f32_32x32x16_bf16(
              pf[mt2], vf[dt], oacc[mt2][dt], 0, 0, 0);
    }
  }

  // ---- epilogue: l row-sums (reduce over l4 groups) ----
  #pragma unroll
  for (int mt = 0; mt < 2; mt++) {
    float s = lacc[mt];
    s += __shfl_xor(s, 16, 64);
    s += __shfl_xor(s, 32, 64);
    if (l4 == 0)
      lpart[(size_t)(ks*2 + ni)*NROWS + Rq0 + mi*32 + mt*16 + l15] = s;
  }

  // ---- epilogue: O stores (bf16) ----
  #pragma unroll
  for (int mt2 = 0; mt2 < 2; mt2++)
    #pragma unroll
    for (int dt = 0; dt < 2; dt++)
      #pragma unroll
      for (int reg = 0; reg < 16; reg++) {
        const int m = mt2*32 + 4*(lane >> 5) + (reg & 3) + 8*(reg >> 2);
        const int d = wave*64 + dt*32 + (lane & 31);
        Opart[((size_t)(ks*NROWS + Rq0 + m))*DIM + d] = f2bf(oacc[mt2][dt][reg]);
      }
}

// ---------------------------------------------------------------------------
// combine: out = (O0+O1) / (l0+l1+l2+l3), Opart in bf16
// ---------------------------------------------------------------------------
__global__ __launch_bounds__(256) void combine(
    const unsigned short* __restrict__ Opart, const float* __restrict__ lpart,
    float* __restrict__ out)
{
  const size_t idx = (size_t)blockIdx.x*256 + threadIdx.x;
  const size_t e = idx*4;
  const int R = (int)(e >> 8);
  ushort4 o0 = *(const ushort4*)(Opart + e);
  ushort4 o1 = *(const ushort4*)(Opart + (size_t)NROWS*DIM + e);
  float ls = lpart[R] + lpart[NROWS + R] + lpart[2*NROWS + R] + lpart[3*NROWS + R];
  float inv = 1.0f / ls;
  float4 o;
  o.x = (bf2f(o0.x) + bf2f(o1.x))*inv;
  o.y = (bf2f(o0.y) + bf2f(o1.y))*inv;
  o.z = (bf2f(o0.z) + bf2f(o1.z))*inv;
  o.w = (bf2f(o0.w) + bf2f(o1.w))*inv;
  *(float4*)(out + e) = o;
}

extern "C" void kernel_launch(void* const* d_in, const int* in_sizes, int n_in,
                              void* d_out, int out_size, void* d_ws, size_t ws_size,
                              hipStream_t stream) {
  const float* Q = (const float*)d_in[0];
  const float* K = (const float*)d_in[1];
  const float* V = (const float*)d_in[2];
  char* ws = (char*)d_ws;
  // ws layout: Kfm 8 MiB | Vfm 8 MiB | Opart(bf16) 16 MiB | lpart 256 KiB
  unsigned short* Kfm   = (unsigned short*)(ws);
  unsigned short* Vfm   = (unsigned short*)(ws + 8388608);
  unsigned short* Opart = (unsigned short*)(ws + 16777216);
  float* lpart = (float*)(ws + 33554432);

  prep<<<1536, 256, 0, stream>>>(K, V, Kfm, Vfm);
  attn<<<512, 256, 0, stream>>>(Q, Kfm, Vfm, Opart, lpart);
  combine<<<4096, 256, 0, stream>>>(Opart, lpart, (float*)d_out);
}